// Round 1
// baseline (439.535 us; speedup 1.0000x reference)
//
#include <hip/hip_runtime.h>

// Radon transform: data (1,1,512,512) f32, angles (256,) f32 -> out (1,1,256,512) f32.
// One thread per (angle, x); y loop split YSPLIT ways across blocks; fp32 atomicAdd.

#define HH 512
#define WW 512
#define NA 256
#define YSPLIT 2

__global__ __launch_bounds__(512) void radon_kernel(
    const float* __restrict__ img, const float* __restrict__ angles,
    float* __restrict__ out)
{
    const int x   = threadIdx.x;                 // 0..511 output column
    const int blk = blockIdx.x;                  // 0..NA*YSPLIT-1
    const int a   = blk >> 1;                    // angle index (YSPLIT=2)
    const int ys  = blk & 1;                     // which y-half

    const float ang = angles[a];
    float s, c;
    sincosf(ang, &s, &c);

    // ix(y) = c*u + s*vy + 255.5 ; iy(y) = -s*u + c*vy + 255.5
    // u = x+0.5-256, vy = y+0.5-256  (derived from affine_grid/grid_sample math, W=H=512)
    const float u  = (float)x + (0.5f - 256.0f);
    const float cu = fmaf(c, u, 255.5f);
    const float cv = fmaf(-s, u, 255.5f);

    float acc = 0.0f;
    const int ybeg = ys * (HH / YSPLIT);
    const int yend = ybeg + (HH / YSPLIT);

#pragma unroll 4
    for (int y = ybeg; y < yend; ++y) {
        const float vy = (float)y + (0.5f - 256.0f);
        const float ix = fmaf(s, vy, cu);
        const float iy = fmaf(c, vy, cv);

        const float fx = floorf(ix);
        const float fy = floorf(iy);
        const int xi = (int)fx;
        const int yi = (int)fy;

        const float wx1 = ix - fx;
        const float wy1 = iy - fy;
        const float wx0 = 1.0f - wx1;
        const float wy0 = 1.0f - wy1;

        // zero-padding: fold validity into the per-axis weights
        const float mwx0 = ((unsigned)xi       < (unsigned)WW) ? wx0 : 0.0f;
        const float mwx1 = ((unsigned)(xi + 1) < (unsigned)WW) ? wx1 : 0.0f;
        const float mwy0 = ((unsigned)yi       < (unsigned)HH) ? wy0 : 0.0f;
        const float mwy1 = ((unsigned)(yi + 1) < (unsigned)HH) ? wy1 : 0.0f;

        const int xc0 = min(max(xi,     0), WW - 1);
        const int xc1 = min(max(xi + 1, 0), WW - 1);
        const int yc0 = min(max(yi,     0), HH - 1);
        const int yc1 = min(max(yi + 1, 0), HH - 1);

        const float* __restrict__ r0 = img + yc0 * WW;
        const float* __restrict__ r1 = img + yc1 * WW;
        const float v00 = r0[xc0];
        const float v01 = r0[xc1];
        const float v10 = r1[xc0];
        const float v11 = r1[xc1];

        acc = fmaf(mwy0, fmaf(mwx1, v01, mwx0 * v00), acc);
        acc = fmaf(mwy1, fmaf(mwx1, v11, mwx0 * v10), acc);
    }

    atomicAdd(&out[a * WW + x], acc);
}

extern "C" void kernel_launch(void* const* d_in, const int* in_sizes, int n_in,
                              void* d_out, int out_size, void* d_ws, size_t ws_size,
                              hipStream_t stream) {
    const float* img    = (const float*)d_in[0];
    const float* angles = (const float*)d_in[1];
    float* out = (float*)d_out;

    // d_out is poisoned 0xAA before every call -> zero it, then atomically accumulate.
    hipMemsetAsync(out, 0, (size_t)out_size * sizeof(float), stream);

    dim3 grid(NA * YSPLIT);
    dim3 block(WW);
    radon_kernel<<<grid, block, 0, stream>>>(img, angles, out);
}

// Round 2
// 368.735 us; speedup vs baseline: 1.1920x; 1.1920x over previous
//
#include <hip/hip_runtime.h>

// Radon transform: data (1,1,512,512) f32, angles (256,) f32 -> out (1,1,256,512) f32.
// Gather-bound kernel. Key trick: keep a transposed copy of the image in d_ws and,
// per angle, sample whichever layout makes consecutive lanes walk along rows
// (scatter factor min(|sin|,|cos|) instead of |sin|).

#define HH 512
#define WW 512
#define NA 256
#define YSPLIT 4

__global__ __launch_bounds__(256) void transpose_kernel(
    const float* __restrict__ in, float* __restrict__ out)
{
    __shared__ float tile[32][33];
    const int bx = blockIdx.x * 32, by = blockIdx.y * 32;
    const int tx = threadIdx.x & 31, ty = threadIdx.x >> 5; // 32x8 threads
#pragma unroll
    for (int i = 0; i < 32; i += 8)
        tile[ty + i][tx] = in[(by + ty + i) * WW + bx + tx];
    __syncthreads();
#pragma unroll
    for (int i = 0; i < 32; i += 8)
        out[(bx + ty + i) * WW + by + tx] = tile[tx][ty + i];
}

__global__ __launch_bounds__(512) void radon_kernel(
    const float* __restrict__ img, const float* __restrict__ imgT,
    const float* __restrict__ angles, float* __restrict__ out, int allowT)
{
    const int x   = threadIdx.x;              // output column, lanes walk x
    const int blk = blockIdx.x;
    const int a   = blk / YSPLIT;
    const int ys  = blk % YSPLIT;

    const float ang = angles[a];
    float s, c;
    sincosf(ang, &s, &c);

    // col coord cx = s*vy + (c*u + 255.5) ; row coord rx = c*vy + (-s*u + 255.5)
    const float u = (float)x + (0.5f - 256.0f);
    float A1 = s, B1 = fmaf(c, u, 255.5f);   // -> ix (column in img)
    float A2 = c, B2 = fmaf(-s, u, 255.5f);  // -> iy (row in img)
    const float* __restrict__ base = img;

    // Per-angle (block-uniform) layout choice: if |s|>|c|, rows scatter fast in img;
    // swap coordinate roles and read the transposed copy instead (identical value).
    if (allowT && fabsf(s) > fabsf(c)) {
        float t;
        t = A1; A1 = A2; A2 = t;
        t = B1; B1 = B2; B2 = t;
        base = imgT;
    }

    float acc = 0.0f;
    const int ybeg = ys * (HH / YSPLIT);
    const int yend = ybeg + (HH / YSPLIT);

#pragma unroll 4
    for (int y = ybeg; y < yend; ++y) {
        const float vy = (float)y + (0.5f - 256.0f);
        const float cx = fmaf(A1, vy, B1);   // column coordinate
        const float rx = fmaf(A2, vy, B2);   // row coordinate

        // lane contributes 0 iff either axis has both taps outside [0,512)
        const bool dead = (cx < -1.0f) | (cx >= 512.0f) | (rx < -1.0f) | (rx >= 512.0f);
        if (__all(dead)) continue;

        const float fc = floorf(cx);
        const float fr = floorf(rx);
        const int ci = (int)fc;
        const int ri = (int)fr;

        const float wc1 = cx - fc, wc0 = 1.0f - wc1;
        const float wr1 = rx - fr, wr0 = 1.0f - wr1;

        // zero-padding folded into per-axis weights
        const float mc0 = ((unsigned)ci       < (unsigned)WW) ? wc0 : 0.0f;
        const float mc1 = ((unsigned)(ci + 1) < (unsigned)WW) ? wc1 : 0.0f;
        const float mr0 = ((unsigned)ri       < (unsigned)HH) ? wr0 : 0.0f;
        const float mr1 = ((unsigned)(ri + 1) < (unsigned)HH) ? wr1 : 0.0f;

        const int cc0 = min(max(ci,     0), WW - 1);
        const int cc1 = min(max(ci + 1, 0), WW - 1);
        const int rc0 = min(max(ri,     0), HH - 1);
        const int rc1 = min(max(ri + 1, 0), HH - 1);

        const float* __restrict__ r0p = base + rc0 * WW;
        const float* __restrict__ r1p = base + rc1 * WW;
        const float v00 = r0p[cc0];
        const float v01 = r0p[cc1];
        const float v10 = r1p[cc0];
        const float v11 = r1p[cc1];

        acc = fmaf(mr0, fmaf(mc1, v01, mc0 * v00), acc);
        acc = fmaf(mr1, fmaf(mc1, v11, mc0 * v10), acc);
    }

    atomicAdd(&out[a * WW + x], acc);
}

extern "C" void kernel_launch(void* const* d_in, const int* in_sizes, int n_in,
                              void* d_out, int out_size, void* d_ws, size_t ws_size,
                              hipStream_t stream) {
    const float* img    = (const float*)d_in[0];
    const float* angles = (const float*)d_in[1];
    float* out  = (float*)d_out;
    float* imgT = (float*)d_ws;

    const int allowT = (ws_size >= (size_t)HH * WW * sizeof(float)) ? 1 : 0;

    hipMemsetAsync(out, 0, (size_t)out_size * sizeof(float), stream);

    if (allowT) {
        dim3 tg(WW / 32, HH / 32);
        transpose_kernel<<<tg, 256, 0, stream>>>(img, imgT);
    }

    radon_kernel<<<dim3(NA * YSPLIT), dim3(WW), 0, stream>>>(img, imgT, angles, out, allowT);
}

// Round 3
// 225.722 us; speedup vs baseline: 1.9472x; 1.6336x over previous
//
#include <hip/hip_runtime.h>

// Radon transform: data (1,1,512,512) f32, angles (256,) f32 -> out (1,1,256,512) f32.
// Block = (angle, 64-col x-chunk). For each 64-row y-chunk, stage the rotated
// patch's bounding box (<=92x92, zero-padded) into LDS, then bilinear-sample
// from LDS (no validity checks needed). Runtime LDS stride (95/97) keeps the
// per-lane bank step |c +- s| >= max(|c|,|s|) >= 0.707 -> ~conflict-free.

#define HH 512
#define WW 512
#define NA 256
#define XC 64
#define YC 64
#define NXC (WW / XC)          // 8 x-chunks
#define NYC (HH / YC)          // 8 y-chunks
#define ROWS_MAX 92
#define STRIDE_MAX 97

__global__ __launch_bounds__(256) void radon_kernel(
    const float* __restrict__ img, const float* __restrict__ angles,
    float* __restrict__ out)
{
    __shared__ float tile[ROWS_MAX * STRIDE_MAX];   // 35.7 KB -> 4 blocks/CU

    const int tid  = threadIdx.x;
    const int lane = tid & 63;     // x_local within chunk
    const int wid  = tid >> 6;     // 0..3 (wave id = y-group)

    const int a  = blockIdx.x >> 3;
    const int x0 = (blockIdx.x & 7) * XC;

    const float ang = angles[a];
    float s, c;
    sincosf(ang, &s, &c);

    // bank(addr/4) = (ri*(stride%32) + ci) % 32 ; pick stride so the per-lane
    // bank step is |c+s| (stride 95 -> ci-ri) or |c-s| (stride 97 -> ci+ri).
    // s >= 0 for angles in [0,pi): c>=0 -> |c+s| >= 0.707 ; c<0 -> |c-s| >= 0.707.
    const int stride = (c >= 0.0f) ? 95 : 97;

    // image coords: cx = c*u + s*v + 255.5 (col), rx = -s*u + c*v + 255.5 (row)
    const float u  = (float)(x0 + lane) + (0.5f - 256.0f);
    const float u0 = (float)x0 + (0.5f - 256.0f);
    const float u1 = u0 + (float)(XC - 1);

    float acc = 0.0f;

    for (int yc = 0; yc < NYC; ++yc) {
        const float v0 = (float)(yc * YC) + (0.5f - 256.0f);
        const float v1 = v0 + (float)(YC - 1);

        // bounding box of all 4 bilinear taps over the chunk (block-uniform)
        const float cu0 = c * u0, cu1 = c * u1;
        const float sv0 = s * v0, sv1 = s * v1;
        const float su0 = -s * u0, su1 = -s * u1;
        const float cv0 = c * v0, cv1 = c * v1;

        const float cx_min = fminf(cu0, cu1) + fminf(sv0, sv1) + 255.5f;
        const float cx_max = fmaxf(cu0, cu1) + fmaxf(sv0, sv1) + 255.5f;
        const float rx_min = fminf(su0, su1) + fminf(cv0, cv1) + 255.5f;
        const float rx_max = fmaxf(su0, su1) + fmaxf(cv0, cv1) + 255.5f;

        const int c_lo = (int)floorf(cx_min);
        const int c_hi = (int)floorf(cx_max) + 1;
        const int r_lo = (int)floorf(rx_min);
        const int r_hi = (int)floorf(rx_max) + 1;
        int bw = c_hi - c_lo + 1;
        int bh = r_hi - r_lo + 1;
        bw = min(bw, STRIDE_MAX);
        bh = min(bh, ROWS_MAX);

        // chunk entirely outside image -> contributes exactly 0 (zero padding)
        if (c_lo > WW - 1 || c_hi < 0 || r_lo > HH - 1 || r_hi < 0) continue;

        __syncthreads();   // previous chunk's sampling must finish before overwrite

        // stage bbox into LDS, zero-padding outside the image
        for (int r = wid; r < bh; r += 4) {
            const int gr = r_lo + r;
            const bool row_ok = ((unsigned)gr < (unsigned)HH);   // wave-uniform
            const float* __restrict__ rowp = img + gr * WW;
            for (int cc = lane; cc < bw; cc += 64) {
                const int gc = c_lo + cc;
                float v = 0.0f;
                if (row_ok) {
                    const int gcl = min(max(gc, 0), WW - 1);
                    const float t = rowp[gcl];
                    v = ((unsigned)gc < (unsigned)WW) ? t : 0.0f;
                }
                tile[r * stride + cc] = v;
            }
        }

        __syncthreads();

        // sample 16 y's per thread from LDS — taps guaranteed inside bbox
        const float bc = fmaf(c, u, 255.5f - (float)c_lo);
        const float br = fmaf(-s, u, 255.5f - (float)r_lo);
        float vy = v0 + (float)(wid * 16);

#pragma unroll 8
        for (int i = 0; i < 16; ++i) {
            const float cxl = fmaf(s, vy, bc);
            const float rxl = fmaf(c, vy, br);
            const float fc = floorf(cxl);
            const float fr = floorf(rxl);
            const int ci = (int)fc;
            const int ri = (int)fr;
            const float wx1 = cxl - fc, wx0 = 1.0f - wx1;
            const float wy1 = rxl - fr, wy0 = 1.0f - wy1;

            const int ad = ri * stride + ci;
            const float v00 = tile[ad];
            const float v01 = tile[ad + 1];
            const float v10 = tile[ad + stride];
            const float v11 = tile[ad + stride + 1];

            const float top = fmaf(wx1, v01, wx0 * v00);
            const float bot = fmaf(wx1, v11, wx0 * v10);
            acc = fmaf(wy0, top, acc);
            acc = fmaf(wy1, bot, acc);
            vy += 1.0f;
        }
    }

    // reduce the 4 y-groups per column and store (each block owns its outputs)
    __syncthreads();
    tile[tid] = acc;
    __syncthreads();
    if (tid < 64) {
        const float r = tile[tid] + tile[64 + tid] + tile[128 + tid] + tile[192 + tid];
        out[a * WW + x0 + tid] = r;
    }
}

extern "C" void kernel_launch(void* const* d_in, const int* in_sizes, int n_in,
                              void* d_out, int out_size, void* d_ws, size_t ws_size,
                              hipStream_t stream) {
    const float* img    = (const float*)d_in[0];
    const float* angles = (const float*)d_in[1];
    float* out = (float*)d_out;

    // every output element is written exactly once -> no memset, no atomics
    radon_kernel<<<dim3(NA * NXC), dim3(256), 0, stream>>>(img, angles, out);
}

// Round 4
// 110.408 us; speedup vs baseline: 3.9810x; 2.0444x over previous
//
#include <hip/hip_runtime.h>

// Radon transform: data (1,1,512,512) f32, angles (256,) f32 -> out (1,1,256,512) f32.
// Block = (angle, 64-col x-chunk), 512 threads (8 waves). For each 64-row y-chunk,
// stage the rotated patch's bbox (<=92x92) into LDS and bilinear-sample from LDS.
// Staging reads a zero-PADDED image copy (in d_ws) via global_load_lds width=16:
// one instruction per bbox row, zero bounds VALU. Runtime LDS stride 95/97 keeps
// per-lane bank step |c +- s| in [1, 1.414] -> ~conflict-free sampling.

#define HH 512
#define WW 512
#define NA 256
#define XC 64
#define YC 64
#define NXC (WW / XC)          // 8 x-chunks
#define NYC (HH / YC)          // 8 y-chunks
#define NW 8                   // waves per block
#define ROWS_MAX 92
#define STRIDE_MAX 97
#define PAD 112                // >= 256*sqrt(2)-256+2
#define PW (WW + 2 * PAD)      // 736
#define PH (HH + 2 * PAD)      // 736

__global__ __launch_bounds__(256) void pad_kernel(
    const float* __restrict__ img, float* __restrict__ P)
{
    const int c = blockIdx.x * 256 + threadIdx.x;
    const int r = blockIdx.y;
    if (c >= PW) return;
    const int gr = r - PAD, gc = c - PAD;
    float v = 0.0f;
    if ((unsigned)gr < (unsigned)HH && (unsigned)gc < (unsigned)WW)
        v = img[gr * WW + gc];
    P[r * PW + c] = v;
}

template <bool PADDED>
__global__ __launch_bounds__(512, 8) void radon_kernel(
    const float* __restrict__ src,   // PADDED ? padded image : raw image
    const float* __restrict__ angles, float* __restrict__ out)
{
    __shared__ float tile[ROWS_MAX * STRIDE_MAX];   // 35.7 KB -> 4 blocks/CU

    const int tid  = threadIdx.x;
    const int lane = tid & 63;
    const int wid  = tid >> 6;     // 0..7

    const int a  = blockIdx.x >> 3;
    const int x0 = (blockIdx.x & 7) * XC;

    float s, c;
    sincosf(angles[a], &s, &c);

    // bank = (ri*stride + ci) % 32; stride 95 (== -1 mod 32) -> bank step c+s,
    // stride 97 (== +1) -> bank step c-s. s>=0: pick so |step| >= 1 always.
    const int stride = (c >= 0.0f) ? 95 : 97;

    const float u  = (float)(x0 + lane) + (0.5f - 256.0f);
    const float u0 = (float)x0 + (0.5f - 256.0f);
    const float u1 = u0 + (float)(XC - 1);

    // origin-shifted padded base: valid for row/col indices in [-PAD, WW+PAD)
    const float* __restrict__ Porg = src + PAD * PW + PAD;

    float acc = 0.0f;

    for (int yc = 0; yc < NYC; ++yc) {
        const float v0 = (float)(yc * YC) + (0.5f - 256.0f);
        const float v1 = v0 + (float)(YC - 1);

        // block-uniform bbox of all bilinear taps for this chunk
        const float cu0 = c * u0, cu1 = c * u1;
        const float sv0 = s * v0, sv1 = s * v1;
        const float su0 = -s * u0, su1 = -s * u1;
        const float cv0 = c * v0, cv1 = c * v1;

        const float cx_min = fminf(cu0, cu1) + fminf(sv0, sv1) + 255.5f;
        const float cx_max = fmaxf(cu0, cu1) + fmaxf(sv0, sv1) + 255.5f;
        const float rx_min = fminf(su0, su1) + fminf(cv0, cv1) + 255.5f;
        const float rx_max = fmaxf(su0, su1) + fmaxf(cv0, cv1) + 255.5f;

        const int c_lo = (int)floorf(cx_min);
        const int c_hi = (int)floorf(cx_max) + 1;
        const int r_lo = (int)floorf(rx_min);
        const int r_hi = (int)floorf(rx_max) + 1;
        int bh = min(r_hi - r_lo + 1, ROWS_MAX);

        // chunk entirely outside image -> contributes exactly 0 (zero padding)
        if (c_lo > WW - 1 || c_hi < 0 || r_lo > HH - 1 || r_hi < 0) continue;

        __syncthreads();   // previous chunk's sampling must finish before overwrite

        if (PADDED) {
            // one global_load_lds_dwordx4 per bbox row: lanes 0..22 each move
            // 16 B -> LDS row base + lane*16 (covers cols 0..91; 368B <= stride*4)
            if (lane < 23) {
                for (int r = wid; r < bh; r += NW) {
                    const float* g = Porg + (r_lo + r) * PW + c_lo + lane * 4;
                    float* l = &tile[r * stride];
                    __builtin_amdgcn_global_load_lds(
                        (__attribute__((address_space(1))) const void*)g,
                        (__attribute__((address_space(3))) void*)l, 16, 0, 0);
                }
            }
        } else {
            const int bw = min(c_hi - c_lo + 1, STRIDE_MAX);
            for (int r = wid; r < bh; r += NW) {
                const int gr = r_lo + r;
                const bool row_ok = ((unsigned)gr < (unsigned)HH);
                const float* __restrict__ rowp = src + gr * WW;
                for (int cc = lane; cc < bw; cc += 64) {
                    const int gc = c_lo + cc;
                    float v = 0.0f;
                    if (row_ok) {
                        const int gcl = min(max(gc, 0), WW - 1);
                        const float t = rowp[gcl];
                        v = ((unsigned)gc < (unsigned)WW) ? t : 0.0f;
                    }
                    tile[r * stride + cc] = v;
                }
            }
        }

        __syncthreads();

        // sample 8 y's per thread from LDS — taps guaranteed inside bbox
        const float bc = fmaf(c, u, 255.5f - (float)c_lo);
        const float br = fmaf(-s, u, 255.5f - (float)r_lo);
        float vy = v0 + (float)(wid * 8);

#pragma unroll
        for (int i = 0; i < 8; ++i) {
            const float cxl = fmaf(s, vy, bc);   // local col coord, >= 0
            const float rxl = fmaf(c, vy, br);   // local row coord, >= 0
            const int ci = (int)cxl;             // == floor for >= 0
            const int ri = (int)rxl;
#if __has_builtin(__builtin_amdgcn_fractf)
            const float wx1 = __builtin_amdgcn_fractf(cxl);
            const float wy1 = __builtin_amdgcn_fractf(rxl);
#else
            const float wx1 = cxl - floorf(cxl);
            const float wy1 = rxl - floorf(rxl);
#endif
            const float wx0 = 1.0f - wx1;
            const float wy0 = 1.0f - wy1;

            __builtin_assume(ri >= 0 && ri < ROWS_MAX);
            __builtin_assume(ci >= 0 && ci < STRIDE_MAX);
            const int ad = ri * stride + ci;

            const float v00 = tile[ad];
            const float v01 = tile[ad + 1];
            const float v10 = tile[ad + stride];
            const float v11 = tile[ad + stride + 1];

            acc = fmaf(wy0, fmaf(wx1, v01, wx0 * v00), acc);
            acc = fmaf(wy1, fmaf(wx1, v11, wx0 * v10), acc);
            vy += 1.0f;
        }
    }

    // reduce the 8 y-groups per column and store (each block owns its outputs)
    __syncthreads();
    tile[tid] = acc;
    __syncthreads();
    if (tid < 64) {
        float r = tile[tid];
#pragma unroll
        for (int k = 1; k < NW; ++k) r += tile[k * 64 + tid];
        out[a * WW + x0 + tid] = r;
    }
}

extern "C" void kernel_launch(void* const* d_in, const int* in_sizes, int n_in,
                              void* d_out, int out_size, void* d_ws, size_t ws_size,
                              hipStream_t stream) {
    const float* img    = (const float*)d_in[0];
    const float* angles = (const float*)d_in[1];
    float* out = (float*)d_out;
    float* P   = (float*)d_ws;

    const bool padded = (ws_size >= (size_t)PW * PH * sizeof(float));

    if (padded) {
        pad_kernel<<<dim3((PW + 255) / 256, PH), 256, 0, stream>>>(img, P);
        radon_kernel<true><<<dim3(NA * NXC), 512, 0, stream>>>(P, angles, out);
    } else {
        radon_kernel<false><<<dim3(NA * NXC), 512, 0, stream>>>(img, angles, out);
    }
}